// Round 5
// baseline (1347.165 us; speedup 1.0000x reference)
//
#include <hip/hip_runtime.h>

// z = conv3x3(x, w) (pad 1, cross-correlation, NCHW/OIHW); LIF scan over t:
//   v = v + (z - v)*0.5 ; s = (v >= 1) ; v = s ? 0 : v
// Numerics hypothesis (R5): harness ref is XLA-CPU/Eigen f32 conv — per output
// element a SINGLE sequential FMA chain over k = (ky, kx, ci), ci INNERMOST,
// acc starts at +0. Padding zeros are fma no-ops (reproduced via zero halo).
// LIF elementwise ops separately rounded (contraction disabled; *0.5 exact).

namespace {
constexpr int T = 16, N = 8, C = 64, H = 64, W = 64;
constexpr int HW  = H * W;      // 4096
constexpr int CHW = C * HW;     // 262144
constexpr int NWT = C * C * 9;  // 36864
}

// Transpose weights (O,I,3,3) -> wt[tap][o][i], tap = ky*3+kx.
__global__ void wtr_kernel(const float* __restrict__ w, float* __restrict__ wt) {
    int i = blockIdx.x * 256 + threadIdx.x;
    if (i >= NWT) return;
    int tap = i % 9;
    int oi  = i / 9;            // o*64 + ci
    wt[tap * (C * C) + oi] = w[i];
}

// Block: 256 threads = 4 waves. Each block: one (n, 8x8 pixel tile), all 64
// out-channels. Wave w: 64 lanes = 64 pixels; out-channels [16w, 16w+16).
__global__ __launch_bounds__(256, 4) void fused_kernel(
    const float* __restrict__ x,
    const float* __restrict__ wt,
    float*       __restrict__ out)
{
#pragma clang fp contract(off)
    __shared__ float xs[64 * 100];   // 64 ci x (10x10 padded tile), 25.6 KB

    const int tid  = threadIdx.x;
    const int wave = __builtin_amdgcn_readfirstlane(tid >> 6);
    const int lane = tid & 63;
    const int px = lane & 7;
    const int py = lane >> 3;
    const int c0 = wave << 4;

    const int bid  = blockIdx.x;      // 512 blocks = 8 n * 64 tiles
    const int n    = bid >> 6;
    const int tile = bid & 63;
    const int th0 = (tile >> 3) << 3;
    const int tw0 = (tile & 7) << 3;

    float v[16];
#pragma unroll
    for (int i = 0; i < 16; ++i) v[i] = 0.0f;

    for (int t = 0; t < T; ++t) {
        const float* xt = x + (size_t)(t * N + n) * CHW;

        __syncthreads();
        // Stage x[t][n][ci][th0-1..th0+8][tw0-1..tw0+8] into LDS (zero halo).
#pragma unroll
        for (int it = 0; it < 25; ++it) {          // 6400 = 25 * 256
            int j  = tid + it * 256;
            int ci = j / 100;
            int r  = j - ci * 100;
            int dy = r / 10;
            int dx = r - dy * 10;
            int hh = th0 - 1 + dy;
            int ww = tw0 - 1 + dx;
            float val = 0.0f;
            if ((unsigned)hh < (unsigned)H && (unsigned)ww < (unsigned)W)
                val = xt[ci * HW + hh * W + ww];
            xs[j] = val;
        }
        __syncthreads();

        float acc[16];
#pragma unroll
        for (int i = 0; i < 16; ++i) acc[i] = 0.0f;

        // Chain per acc[cc]: k = tap*64 + ci ascending, one fmaf per k.
        // (tap outer, ci inner => ci is the innermost contraction index.)
#pragma unroll
        for (int tap = 0; tap < 9; ++tap) {
            const int ky = tap / 3, kx = tap - 3 * ky;
            const float* xrow = &xs[(py + ky) * 10 + (px + kx)];
            const float* wrow = wt + tap * (C * C) + c0 * C;   // wave-uniform
#pragma unroll 4
            for (int ci = 0; ci < C; ++ci) {
                const float xv = xrow[ci * 100];
#pragma unroll
                for (int cc = 0; cc < 16; ++cc)
                    acc[cc] = fmaf(wrow[cc * C + ci], xv, acc[cc]);
            }
        }

        // LIF: sub, *0.5 (exact), add — each separately rounded; hard reset.
        float* ot = out + (size_t)(t * N + n) * CHW;
        const int pbase = (th0 + py) * W + (tw0 + px);
#pragma unroll
        for (int cc = 0; cc < 16; ++cc) {
            float vv = v[cc];
            float d  = acc[cc] - vv;
            float h  = d * 0.5f;
            vv = vv + h;
            float s;
            if (vv >= 1.0f) { s = 1.0f; vv = 0.0f; } else { s = 0.0f; }
            v[cc] = vv;
            ot[(c0 + cc) * HW + pbase] = s;
        }
    }
}

extern "C" void kernel_launch(void* const* d_in, const int* in_sizes, int n_in,
                              void* d_out, int out_size, void* d_ws, size_t ws_size,
                              hipStream_t stream) {
    const float* x = (const float*)d_in[0];
    const float* w = (const float*)d_in[1];
    if (n_in >= 2 && in_sizes[0] < in_sizes[1]) {   // defensive: pick by size
        const float* tmp = x; x = w; w = tmp;
    }
    float* out = (float*)d_out;
    float* wt  = (float*)d_ws;                       // 36864 floats = 144 KB

    wtr_kernel<<<(NWT + 255) / 256, 256, 0, stream>>>(w, wt);
    fused_kernel<<<N * 64, 256, 0, stream>>>(x, wt, out);
}

// Round 6
// 856.148 us; speedup vs baseline: 1.5735x; 1.5735x over previous
//
#include <hip/hip_runtime.h>

// z = conv3x3(x, w) (pad 1, cross-correlation, NCHW/OIHW); LIF scan over t:
//   v = v + (z - v)*0.5 ; s = (v >= 1) ; v = s ? 0 : v
// NUMERICS INVARIANT (verified bit-exact in R5): per output element the conv
// is a SINGLE sequential f32 FMA chain over k = (tap, ci), tap = ky*3+kx
// outer, ci INNERMOST (Eigen/XLA-CPU order), acc starts at 0; padding taps are
// exact fma no-ops (zero halo). LIF ops separately rounded; *0.5 exact.
// Only load scheduling may change; FMA order must never change.

namespace {
constexpr int T = 16, N = 8, C = 64, H = 64, W = 64;
constexpr int HW  = H * W;      // 4096
constexpr int CHW = C * HW;     // 262144
constexpr int NWT = C * C * 9;  // 36864
constexpr int PSTR = 68;        // LDS pos-stride in floats (pad: 64+4)
}

// Transpose weights (O,I,3,3) -> wt2[tap][ci][cout]: per (tap,ci) the couts
// are contiguous -> one s_load_dwordx8 per wave per (tap,ci).
__global__ void wtr_kernel(const float* __restrict__ w, float* __restrict__ wt2) {
    int i = blockIdx.x * 256 + threadIdx.x;     // i = (cout*64 + ci)*9 + tap
    if (i >= NWT) return;
    int tap  = i % 9;
    int rem  = i / 9;
    int ci   = rem % 64;
    int cout = rem / 64;
    wt2[(tap * 64 + ci) * 64 + cout] = w[i];
}

// Block: 512 threads = 8 waves = one (n, 8x8 pixel tile), all 64 out-channels.
// Wave w: 64 lanes = 64 pixels; out-channels [8w, 8w+8). 512 blocks total ->
// 2 blocks/CU, 16 waves/CU. LDS: transposed x-tile xs[pos*68 + ci], 27.2 KB.
__global__ __launch_bounds__(512, 4) void fused_kernel(
    const float* __restrict__ x,
    const float* __restrict__ wt2,
    float*       __restrict__ out)
{
#pragma clang fp contract(off)
    __shared__ float xs[100 * PSTR];   // pos = dy*10+dx in [0,100), ci in [0,64)

    const int tid  = threadIdx.x;
    const int wave = __builtin_amdgcn_readfirstlane(tid >> 6);
    const int lane = tid & 63;
    const int px = lane & 7;
    const int py = lane >> 3;
    const int c0 = wave << 3;          // 8 couts per wave

    const int bid  = blockIdx.x;       // 512 blocks = 8 n * 64 tiles
    const int n    = bid >> 6;
    const int tile = bid & 63;
    const int th0 = (tile >> 3) << 3;
    const int tw0 = (tile & 7) << 3;

    float v[8];
#pragma unroll
    for (int i = 0; i < 8; ++i) v[i] = 0.0f;

    for (int t = 0; t < T; ++t) {
        const float* xt = x + (size_t)(t * N + n) * CHW;

        __syncthreads();
        // Stage x[t][n][ci][th0-1..+8][tw0-1..+8] transposed into LDS
        // (zero halo). j = ci*100 + r keeps global reads row-contiguous.
#pragma unroll
        for (int it = 0; it < 13; ++it) {          // 6400 elems, 512 threads
            int j = tid + it * 512;
            if (j < 6400) {
                int ci = j / 100;
                int r  = j - ci * 100;
                int dy = r / 10;
                int dx = r - dy * 10;
                int hh = th0 - 1 + dy;
                int ww = tw0 - 1 + dx;
                float val = 0.0f;
                if ((unsigned)hh < (unsigned)H && (unsigned)ww < (unsigned)W)
                    val = xt[ci * HW + hh * W + ww];
                xs[r * PSTR + ci] = val;
            }
        }
        __syncthreads();

        float acc[8];
#pragma unroll
        for (int i = 0; i < 8; ++i) acc[i] = 0.0f;

        // Chain per acc[cc]: tap outer (9), ci 0..63 ascending inner.
        // x reads: one float4 (ds_read_b128) per 4 ci; weights: wp contiguous
        // 8 floats at wave-uniform address (s_load_dwordx8).
#pragma unroll
        for (int tap = 0; tap < 9; ++tap) {
            const int ky = tap / 3, kx = tap - 3 * ky;
            const int pos = (py + ky) * 10 + (px + kx);
            const float4* xp = (const float4*)xs + pos * (PSTR / 4);
            const float* wtap = wt2 + tap * 4096 + c0;
#pragma unroll 4
            for (int cib = 0; cib < 16; ++cib) {
                const float4 xv = xp[cib];
                const float* wp = wtap + cib * 256;   // (tap, ci=4*cib) block
#pragma unroll
                for (int cc = 0; cc < 8; ++cc)
                    acc[cc] = fmaf(wp[cc], xv.x, acc[cc]);
#pragma unroll
                for (int cc = 0; cc < 8; ++cc)
                    acc[cc] = fmaf(wp[64 + cc], xv.y, acc[cc]);
#pragma unroll
                for (int cc = 0; cc < 8; ++cc)
                    acc[cc] = fmaf(wp[128 + cc], xv.z, acc[cc]);
#pragma unroll
                for (int cc = 0; cc < 8; ++cc)
                    acc[cc] = fmaf(wp[192 + cc], xv.w, acc[cc]);
            }
        }

        // LIF: sub, *0.5 (exact), add — each separately rounded; hard reset.
        float* ot = out + (size_t)(t * N + n) * CHW;
        const int pbase = (th0 + py) * W + (tw0 + px);
#pragma unroll
        for (int cc = 0; cc < 8; ++cc) {
            float vv = v[cc];
            float d  = acc[cc] - vv;
            float h  = d * 0.5f;
            vv = vv + h;
            float s;
            if (vv >= 1.0f) { s = 1.0f; vv = 0.0f; } else { s = 0.0f; }
            v[cc] = vv;
            ot[(c0 + cc) * HW + pbase] = s;
        }
    }
}

extern "C" void kernel_launch(void* const* d_in, const int* in_sizes, int n_in,
                              void* d_out, int out_size, void* d_ws, size_t ws_size,
                              hipStream_t stream) {
    const float* x = (const float*)d_in[0];
    const float* w = (const float*)d_in[1];
    if (n_in >= 2 && in_sizes[0] < in_sizes[1]) {   // defensive: pick by size
        const float* tmp = x; x = w; w = tmp;
    }
    float* out = (float*)d_out;
    float* wt2 = (float*)d_ws;                       // 36864 floats = 144 KB

    wtr_kernel<<<(NWT + 255) / 256, 256, 0, stream>>>(w, wt2);
    fused_kernel<<<N * 64, 512, 0, stream>>>(x, wt2, out);
}

// Round 7
// 678.553 us; speedup vs baseline: 1.9854x; 1.2617x over previous
//
#include <hip/hip_runtime.h>

// z = conv3x3(x, w) (pad 1, cross-correlation, NCHW/OIHW); LIF scan over t:
//   v = v + (z - v)*0.5 ; s = (v >= 1) ; v = s ? 0 : v
// NUMERICS INVARIANT (verified bit-exact R5/R6): per output element the conv
// is a SINGLE sequential f32 FMA chain over k = (tap, ci), tap = ky*3+kx
// outer, ci INNERMOST (Eigen/XLA-CPU order), acc starts at 0; padding taps are
// exact fma no-ops (zero halo). LIF ops separately rounded; *0.5 exact.
// R7: conv and LIF split into two kernels; z round-trips through d_out
// (in-place LIF — each element owned by one thread). Conv: 8192 blocks
// (t,n,tile), 4 waves x 16 couts -> 2x FMA:LDS ratio, ~5 blocks/CU.

namespace {
constexpr int T = 16, N = 8, C = 64, H = 64, W = 64;
constexpr int HW   = H * W;       // 4096
constexpr int CHW  = C * HW;      // 262144
constexpr int NCHW = N * CHW;     // 2097152
constexpr int NWT  = C * C * 9;   // 36864
constexpr int PSTR = 68;          // LDS pos-stride in floats (64+4 pad)
}

// Transpose weights (O,I,3,3) -> wt2[tap][ci][cout]: per (tap,ci) couts are
// contiguous -> wave-uniform s_load of 16 floats per wave per (tap,ci).
__global__ void wtr_kernel(const float* __restrict__ w, float* __restrict__ wt2) {
    int i = blockIdx.x * 256 + threadIdx.x;     // i = (cout*64 + ci)*9 + tap
    if (i >= NWT) return;
    int tap  = i % 9;
    int rem  = i / 9;
    int ci   = rem % 64;
    int cout = rem / 64;
    wt2[(tap * 64 + ci) * 64 + cout] = w[i];
}

// Conv only. Block: 256 threads = 4 waves = one (t, n, 8x8 tile), 64 couts.
// Wave w: 64 lanes = 64 pixels; couts [16w, 16w+16). Writes z into `zo`.
__global__ __launch_bounds__(256, 5) void conv_kernel(
    const float* __restrict__ x,
    const float* __restrict__ wt2,
    float*       __restrict__ zo)
{
#pragma clang fp contract(off)
    __shared__ float xs[100 * PSTR];   // pos = dy*10+dx in [0,100), ci in [0,64)

    const int tid  = threadIdx.x;
    const int wave = __builtin_amdgcn_readfirstlane(tid >> 6);
    const int lane = tid & 63;
    const int px = lane & 7;
    const int py = lane >> 3;
    const int c0 = wave << 4;          // 16 couts per wave

    const int bid  = blockIdx.x;       // 8192 = 16 t * 8 n * 64 tiles
    const int t    = bid >> 9;
    const int r    = bid & 511;
    const int n    = r >> 6;
    const int tile = r & 63;
    const int th0 = (tile >> 3) << 3;
    const int tw0 = (tile & 7) << 3;

    const float* xt = x + (size_t)(t * N + n) * CHW;

    // Stage x[t][n][ci][th0-1..+8][tw0-1..+8] transposed into LDS (zero halo).
#pragma unroll
    for (int it = 0; it < 25; ++it) {              // 6400 = 25 * 256
        int j  = tid + it * 256;
        int ci = j / 100;
        int rr = j - ci * 100;
        int dy = rr / 10;
        int dx = rr - dy * 10;
        int hh = th0 - 1 + dy;
        int ww = tw0 - 1 + dx;
        float val = 0.0f;
        if ((unsigned)hh < (unsigned)H && (unsigned)ww < (unsigned)W)
            val = xt[ci * HW + hh * W + ww];
        xs[rr * PSTR + ci] = val;
    }
    __syncthreads();

    float acc[16];
#pragma unroll
    for (int i = 0; i < 16; ++i) acc[i] = 0.0f;

    // Chain per acc[cc]: tap outer (9), ci 0..63 ascending inner; one fmaf
    // per k; only load scheduling varies, never FMA order.
    for (int tap = 0; tap < 9; ++tap) {
        const int ky = tap / 3, kx = tap - 3 * ky;
        const int pos = (py + ky) * 10 + (px + kx);
        const float4* xp = (const float4*)xs + pos * (PSTR / 4);
        const float* wtap = wt2 + tap * 4096 + c0;   // wave-uniform
#pragma unroll 2
        for (int cib = 0; cib < 16; ++cib) {
            const float4 xv = xp[cib];
            const float* wp = wtap + cib * 256;      // (tap, ci=4*cib) block
#pragma unroll
            for (int cc = 0; cc < 16; ++cc)
                acc[cc] = fmaf(wp[cc], xv.x, acc[cc]);
#pragma unroll
            for (int cc = 0; cc < 16; ++cc)
                acc[cc] = fmaf(wp[64 + cc], xv.y, acc[cc]);
#pragma unroll
            for (int cc = 0; cc < 16; ++cc)
                acc[cc] = fmaf(wp[128 + cc], xv.z, acc[cc]);
#pragma unroll
            for (int cc = 0; cc < 16; ++cc)
                acc[cc] = fmaf(wp[192 + cc], xv.w, acc[cc]);
        }
    }

    float* zt = zo + (size_t)(t * N + n) * CHW;
    const int pbase = (th0 + py) * W + (tw0 + px);
#pragma unroll
    for (int cc = 0; cc < 16; ++cc)
        zt[(c0 + cc) * HW + pbase] = acc[cc];
}

// LIF scan, in-place on zo (reads z, writes 0/1 spikes). One thread per
// (n,c,h,w) neuron; t-loop carries v in a register. Elementwise ops
// separately rounded (*0.5 exact, so fma-contraction couldn't change bits,
// but contraction is disabled anyway).
__global__ void lif_kernel(float* __restrict__ zo) {
#pragma clang fp contract(off)
    const int gid = blockIdx.x * 256 + threadIdx.x;   // [0, NCHW)
    float v = 0.0f;
#pragma unroll
    for (int t = 0; t < T; ++t) {
        float* p = zo + (size_t)t * NCHW + gid;
        float z = *p;
        float d = z - v;
        float h = d * 0.5f;
        v = v + h;
        float s;
        if (v >= 1.0f) { s = 1.0f; v = 0.0f; } else { s = 0.0f; }
        *p = s;
    }
}

extern "C" void kernel_launch(void* const* d_in, const int* in_sizes, int n_in,
                              void* d_out, int out_size, void* d_ws, size_t ws_size,
                              hipStream_t stream) {
    const float* x = (const float*)d_in[0];
    const float* w = (const float*)d_in[1];
    if (n_in >= 2 && in_sizes[0] < in_sizes[1]) {   // defensive: pick by size
        const float* tmp = x; x = w; w = tmp;
    }
    float* out = (float*)d_out;
    float* wt2 = (float*)d_ws;                       // 36864 floats = 144 KB

    wtr_kernel<<<(NWT + 255) / 256, 256, 0, stream>>>(w, wt2);
    conv_kernel<<<T * N * 64, 256, 0, stream>>>(x, wt2, out);
    lif_kernel<<<NCHW / 256, 256, 0, stream>>>(out);
}